// Round 12
// baseline (5855.184 us; speedup 1.0000x reference)
//
#include <hip/hip_runtime.h>
#include <hip/hip_bf16.h>
#include <stdint.h>

typedef short bf16x8 __attribute__((ext_vector_type(8)));
typedef float f32x4 __attribute__((ext_vector_type(4)));

#define B_ 16
#define S_ 2048
#define H_ 512
#define NG 2048      // 4*H
#define KA 827
#define KP 832
#define NPOS (B_*S_)

// ---- workspace layout (bytes) ----
// ring overlays xaug (dead after gemmk; sentk re-initializes; its plain stores
// are L3-visible at dispatch end — proven by every passing round).
// ring: 2048 slots x 16 KiB, NO-REUSE, wave-major:
//   producer wave W's 128 h-values (8 h x 16 batches, bf16) live CONTIGUOUSLY at
//   u64 index W*32 + b*2 + kq  (kq in {0,1})  -> 4 cache lines per producer.
// ALL steps publish (incl. t=2047): the ring doubles as the bf16 ys archive that
// outk expands to f32 afterwards (R10-proven).
#define OFF_XAUG 0                     // NPOS*KP*2 = 54,525,952
#define OFF_WIHB 54525952              // NG*KP*2   =  3,407,872
#define OFF_G    57933824              // NPOS*NG*2 = 134,217,728 (ends 192,151,552)
#define OFF_RING 0                     // 33,554,432 B (< xaug size)
#define RING_U64_PER_SLOT 2048
#define SENT32 0x7F807F80u
#define SENT64 0x7F807F807F807F80ull   // 4x bf16 +inf; |h|<1 can never produce this

__device__ __forceinline__ unsigned short f2bf(float f){
  union { float f; unsigned u; } v; v.f = f;
  unsigned u = v.u;
  unsigned r = (u + 0x7FFFu + ((u >> 16) & 1u)) >> 16;
  return (unsigned short)r;
}
__device__ __forceinline__ float bf2f(unsigned short s){
  union { unsigned u; float f; } v; v.u = ((unsigned)s) << 16;
  return v.f;
}
__device__ __forceinline__ float sigf(float x){ return 1.0f / (1.0f + __expf(-x)); }
__device__ __forceinline__ float tanhfast(float x){ return 1.0f - 2.0f / (__expf(2.0f*x) + 1.0f); }

// ---------------- windowed signatures -> x_aug (bf16, K padded to 832) ----------------
__global__ __launch_bounds__(256) void sigk(const float* __restrict__ x,
                                            unsigned short* __restrict__ xaug){
  const int bid = blockIdx.x;
  const int s = bid >> 4, b = bid & 15;
  const int tid = threadIdx.x;
  __shared__ float win[10][9];
  __shared__ float s1b[2][9];
  __shared__ float s2b[2][81];
  if (tid < 90){
    int w = tid / 9, d = tid - w*9;
    int idx = s - 9 + w; if (idx < 0) idx = 0;
    win[w][d] = (d < 8) ? x[((size_t)b*S_ + idx)*8 + d] : (float)idx * (1.0f/2047.0f);
  }
  if (tid < 81) s2b[0][tid] = 0.0f;
  if (tid < 9)  s1b[0][tid] = 0.0f;
  __syncthreads();
  const int i0 = tid / 81;
  const int jj = (tid / 9) % 9;
  const int kk = tid % 9;
  float r0 = 0.0f, r1 = 0.0f, r2 = 0.0f;
  int p = 0;
  for (int w = 0; w < 10; ++w){
    if (tid < 243){
      float dj  = win[w][jj]   - (w ? win[w-1][jj]   : 0.0f);
      float dk  = win[w][kk]   - (w ? win[w-1][kk]   : 0.0f);
      float di0 = win[w][i0]   - (w ? win[w-1][i0]   : 0.0f);
      float di1 = win[w][i0+3] - (w ? win[w-1][i0+3] : 0.0f);
      float di2 = win[w][i0+6] - (w ? win[w-1][i0+6] : 0.0f);
      float e2 = 0.5f * dj * dk;
      float e3 = dj * dk * (1.0f/6.0f);
      r0 += s2b[p][i0*9+jj]*dk     + s1b[p][i0]*e2   + di0*e3;
      r1 += s2b[p][(i0+3)*9+jj]*dk + s1b[p][i0+3]*e2 + di1*e3;
      r2 += s2b[p][(i0+6)*9+jj]*dk + s1b[p][i0+6]*e2 + di2*e3;
    }
    if (tid < 81){
      int si = tid / 9, sj = tid - si*9;
      float dsi = win[w][si] - (w ? win[w-1][si] : 0.0f);
      float dsj = win[w][sj] - (w ? win[w-1][sj] : 0.0f);
      s2b[p^1][tid] = s2b[p][tid] + s1b[p][si]*dsj + 0.5f*dsi*dsj;
    }
    if (tid < 9){
      float dt = win[w][tid] - (w ? win[w-1][tid] : 0.0f);
      s1b[p^1][tid] = s1b[p][tid] + dt;
    }
    __syncthreads();
    p ^= 1;
  }
  unsigned short* row = xaug + (size_t)bid * KP;
  if (tid < 8)  row[tid]      = f2bf(x[((size_t)b*S_ + s)*8 + tid]);
  if (tid < 9)  row[8 + tid]  = f2bf(s1b[p][tid]);
  if (tid < 81) row[17 + tid] = f2bf(s2b[p][tid]);
  if (tid < 243){
    row[98 + tid]       = f2bf(r0);
    row[98 + tid + 243] = f2bf(r1);
    row[98 + tid + 486] = f2bf(r2);
  }
  if (tid < KP - KA) row[KA + tid] = 0;
}

// ---------------- W_ih f32 (2048x827) -> bf16 (2048x832 padded) ----------------
__global__ void convk(const float* __restrict__ W, unsigned short* __restrict__ o){
  int idx = blockIdx.x*256 + threadIdx.x;
  if (idx >= NG*KP) return;
  int n = idx / KP, k = idx - n*KP;
  o[idx] = (k < KA) ? f2bf(W[(size_t)n*KA + k]) : (unsigned short)0;
}

// ---------------- G = x_aug @ W_ih.T  (bf16 out) ----------------
__global__ __launch_bounds__(256) void gemmk(const unsigned short* __restrict__ A,
                                             const unsigned short* __restrict__ Bw,
                                             unsigned short* __restrict__ G){
  __shared__ unsigned short as[128][40];
  __shared__ unsigned short bs[128][40];
  const int tid = threadIdx.x;
  const int l = tid & 63, w = tid >> 6;
  const int wr = w >> 1, wc = w & 1;
  const int M0 = blockIdx.x * 128, N0 = blockIdx.y * 128;
  f32x4 acc[4][4];
  for (int i=0;i<4;i++) for (int j2=0;j2<4;j2++) acc[i][j2] = (f32x4){0,0,0,0};
  const int lrow = l & 15, kq8 = (l >> 4) * 8;
  for (int kt = 0; kt < 26; ++kt){
    const int kbase = kt * 32;
    for (int c = tid; c < 512; c += 256){
      int row = c >> 2, kc = (c & 3) * 8;
      uint4 va = *(const uint4*)(A  + (size_t)(M0 + row)*KP + kbase + kc);
      *(uint4*)(&as[row][kc]) = va;
      uint4 vb = *(const uint4*)(Bw + (size_t)(N0 + row)*KP + kbase + kc);
      *(uint4*)(&bs[row][kc]) = vb;
    }
    __syncthreads();
    bf16x8 af[4], bfv[4];
    for (int i=0;i<4;i++)    af[i]  = *(const bf16x8*)(&as[wr*64 + i*16 + lrow][kq8]);
    for (int j2=0;j2<4;j2++) bfv[j2] = *(const bf16x8*)(&bs[wc*64 + j2*16 + lrow][kq8]);
    for (int i=0;i<4;i++)
      for (int j2=0;j2<4;j2++)
        acc[i][j2] = __builtin_amdgcn_mfma_f32_16x16x32_bf16(af[i], bfv[j2], acc[i][j2], 0, 0, 0);
    __syncthreads();
  }
  const int rq = (l >> 4) * 4;
  for (int i=0;i<4;i++){
    for (int q=0;q<4;q++){
      int grow_ = M0 + wr*64 + i*16 + rq + q;
      unsigned short* gout = G + (size_t)grow_*NG + N0 + wc*64 + lrow;
      for (int j2=0;j2<4;j2++)
        gout[j2*16] = f2bf(acc[i][j2][q]);
    }
  }
}

// ---------------- init: sentinel-fill the 32 MiB no-reuse ring ----------------
__global__ __launch_bounds__(256) void sentk(uint4* __restrict__ ring){
  const size_t i = (size_t)blockIdx.x*256 + threadIdx.x;   // 1024 blocks -> 262144 threads
  uint4 s; s.x = SENT32; s.y = SENT32; s.z = SENT32; s.w = SENT32;
  #pragma unroll
  for (int k = 0; k < 8; ++k)
    ring[i + (size_t)k*262144] = s;                        // 2,097,152 uint4 = 32 MiB
}

// ---------------- LSTM recurrence: 16 blocks x 4 waves, block-cooperative sweep ----------------
// wave W = blockIdx*4+wid owns h indices [W*8, W*8+8) with ALL 4 gates (R11 compute verbatim).
// sweep: 256 threads cooperatively atomic-load the whole 16 KiB slot (8 coalesced u64
// loads/thread, dense batched, FULL redo on retry — R10 lesson), block-wide readiness
// via LDS flags + barrier; on clean, deposit slot image in LDS and each wave reads its
// B-fragments with ds_read_b128. 4x fewer L3 atomic requests than per-wave sweeps.
// publish: per-low-lane agent atomic exchange, EVERY step (ring = ys archive), unchanged.
__global__ __launch_bounds__(256, 1) void recurk(const float* __restrict__ Whh,
    const float* __restrict__ bih, const float* __restrict__ bhh,
    const unsigned short* __restrict__ G, float* __restrict__ out,
    unsigned long long* __restrict__ ring){
  __shared__ unsigned long long hbuf[RING_U64_PER_SLOT];   // 16 KiB slot image
  __shared__ int wflag[4];
  const int tid = threadIdx.x;
  const int wid = tid >> 6;
  const int l = tid & 63;
  const int W = (int)blockIdx.x * 4 + wid;   // 4 consecutive W per block -> G lines shared in L1
  const int b = l & 15, kq = l >> 4;
  const int hbase = W * 8;

  // A fragments resident in registers (128 VGPRs)
  bf16x8 a0[16], a1[16];
  {
    const int p = l & 15;
    const int arow0 = (p < 8) ? (hbase + p) : (512 + hbase + (p - 8));
    const int arow1 = arow0 + 1024;
    const float* w0 = Whh + (size_t)arow0 * H_;
    const float* w1 = Whh + (size_t)arow1 * H_;
    for (int kk2 = 0; kk2 < 16; ++kk2){
      const int k0 = kk2*32 + kq*8;
      float4 v0 = *(const float4*)(w0 + k0);
      float4 v1 = *(const float4*)(w0 + k0 + 4);
      bf16x8 av;
      av[0]=(short)f2bf(v0.x); av[1]=(short)f2bf(v0.y); av[2]=(short)f2bf(v0.z); av[3]=(short)f2bf(v0.w);
      av[4]=(short)f2bf(v1.x); av[5]=(short)f2bf(v1.y); av[6]=(short)f2bf(v1.z); av[7]=(short)f2bf(v1.w);
      a0[kk2] = av;
      float4 u0 = *(const float4*)(w1 + k0);
      float4 u1 = *(const float4*)(w1 + k0 + 4);
      bf16x8 bv2;
      bv2[0]=(short)f2bf(u0.x); bv2[1]=(short)f2bf(u0.y); bv2[2]=(short)f2bf(u0.z); bv2[3]=(short)f2bf(u0.w);
      bv2[4]=(short)f2bf(u1.x); bv2[5]=(short)f2bf(u1.y); bv2[6]=(short)f2bf(u1.z); bv2[7]=(short)f2bf(u1.w);
      a1[kk2] = bv2;
    }
  }
  const int col0 = ((kq < 2) ? (kq*4) : (512 + (kq-2)*4)) + hbase;
  const int col1 = col0 + 1024;
  float bias0[4], bias1[4];
  #pragma unroll
  for (int q=0;q<4;q++){
    bias0[q] = bih[col0+q] + bhh[col0+q];
    bias1[q] = bih[col1+q] + bhh[col1+q];
  }
  const bool low = (kq < 2);
  const int hcol = hbase + (low ? kq*4 : (kq-2)*4);
  const size_t ownw = (size_t)W*32 + b*2 + kq;   // low-lane's ring word (u64 idx in slot)
  float cr[4] = {0,0,0,0};

  for (int t = 0; t < S_; ++t){
    // G prefetch (cacheable) issued before the sweep; HBM latency hides under it
    const unsigned short* gp = G + ((size_t)t*16 + b) * NG;
    const short4 g0 = *(const short4*)(gp + col0);
    const short4 g1 = *(const short4*)(gp + col1);

    f32x4 acc0 = (f32x4){0,0,0,0}, acc0b = (f32x4){0,0,0,0};
    f32x4 acc1 = (f32x4){0,0,0,0}, acc1b = (f32x4){0,0,0,0};
    if (t){
      // ---- block-cooperative sentinel sweep: 8 coalesced atomic u64 loads/thread ----
      const unsigned long long* sp = ring + (size_t)(t-1)*RING_U64_PER_SLOT;
      unsigned long long rv[8];
      for (;;){
        #pragma unroll
        for (int j = 0; j < 8; ++j)
          rv[j] = __hip_atomic_load(sp + tid + j*256, __ATOMIC_RELAXED, __HIP_MEMORY_SCOPE_AGENT);
        unsigned ok = 1;
        #pragma unroll
        for (int j = 0; j < 8; ++j) ok &= (rv[j] != SENT64);
        const int wok = __all((int)ok);
        if (l == 0) wflag[wid] = wok;
        __syncthreads();
        const int allok = wflag[0] & wflag[1] & wflag[2] & wflag[3];
        __syncthreads();   // protect wflag reuse next round
        if (allok) break;
      }
      // deposit slot image, redistribute via LDS
      #pragma unroll
      for (int j = 0; j < 8; ++j) hbuf[tid + j*256] = rv[j];
      __syncthreads();
      uint4 hv[16];
      #pragma unroll
      for (int i = 0; i < 16; ++i)
        hv[i] = *(const uint4*)&hbuf[(i*4 + kq)*32 + b*2];
      #pragma unroll
      for (int i = 0; i < 8; ++i){
        bf16x8 bv0 = __builtin_bit_cast(bf16x8, hv[2*i]);
        acc0  = __builtin_amdgcn_mfma_f32_16x16x32_bf16(a0[2*i],   bv0, acc0,  0, 0, 0);
        acc1  = __builtin_amdgcn_mfma_f32_16x16x32_bf16(a1[2*i],   bv0, acc1,  0, 0, 0);
        bf16x8 bv1 = __builtin_bit_cast(bf16x8, hv[2*i+1]);
        acc0b = __builtin_amdgcn_mfma_f32_16x16x32_bf16(a0[2*i+1], bv1, acc0b, 0, 0, 0);
        acc1b = __builtin_amdgcn_mfma_f32_16x16x32_bf16(a1[2*i+1], bv1, acc1b, 0, 0, 0);
      }
    }
    float ga0[4] = { bf2f((unsigned short)g0.x), bf2f((unsigned short)g0.y),
                     bf2f((unsigned short)g0.z), bf2f((unsigned short)g0.w) };
    float ga1[4] = { bf2f((unsigned short)g1.x), bf2f((unsigned short)g1.y),
                     bf2f((unsigned short)g1.z), bf2f((unsigned short)g1.w) };
    float own0[4], own1[4], oth0[4], oth1[4];
    #pragma unroll
    for (int q=0;q<4;q++){
      own0[q] = (acc0[q] + acc0b[q]) + ga0[q] + bias0[q];
      own1[q] = (acc1[q] + acc1b[q]) + ga1[q] + bias1[q];
    }
    #pragma unroll
    for (int q=0;q<4;q++){
      oth0[q] = __shfl_xor(own0[q], 32, 64);
      oth1[q] = __shfl_xor(own1[q], 32, 64);
    }
    float h4[4];
    #pragma unroll
    for (int q=0;q<4;q++){
      float iv = low ? own0[q] : oth0[q];
      float fv = low ? oth0[q] : own0[q];
      float gv = low ? own1[q] : oth1[q];
      float ov = low ? oth1[q] : own1[q];
      cr[q] = sigf(fv)*cr[q] + sigf(iv)*tanhfast(gv);
      h4[q] = sigf(ov)*tanhfast(cr[q]);
    }
    if (low){
      // publish EVERY step: data is both the next-step signal and the ys archive
      unsigned long long pk = (unsigned long long)f2bf(h4[0])
                            | ((unsigned long long)f2bf(h4[1]) << 16)
                            | ((unsigned long long)f2bf(h4[2]) << 32)
                            | ((unsigned long long)f2bf(h4[3]) << 48);
      __hip_atomic_exchange(ring + (size_t)t*RING_U64_PER_SLOT + ownw,
                            pk, __ATOMIC_RELAXED, __HIP_MEMORY_SCOPE_AGENT);
      if (t == S_ - 1){
        float* hn = out + (size_t)B_*S_*H_;
        float* cn = hn + B_*H_;
        #pragma unroll
        for (int q=0;q<4;q++){
          hn[b*H_ + hcol + q] = h4[q];
          cn[b*H_ + hcol + q] = cr[q];
        }
      }
    }
  }
}

// ---------------- outk: expand ring (bf16 ys archive) -> out f32, fully coalesced ----------------
__global__ __launch_bounds__(256) void outk(const unsigned long long* __restrict__ ring,
                                            float* __restrict__ out){
  const size_t idx = (size_t)blockIdx.x*256 + threadIdx.x;   // 16*2048*128 = 4,194,304
  const int w = (int)(idx & 127);          // group of 4 h-cols
  const size_t bt = idx >> 7;
  const int t = (int)(bt & 2047);
  const int b = (int)(bt >> 11);
  const int hcol = w * 4;
  const int W = hcol >> 3;
  const int kq = (hcol >> 2) & 1;
  unsigned long long v = ring[(size_t)t*RING_U64_PER_SLOT + (size_t)W*32 + b*2 + kq];
  float4 o;
  o.x = bf2f((unsigned short)(v));
  o.y = bf2f((unsigned short)(v >> 16));
  o.z = bf2f((unsigned short)(v >> 32));
  o.w = bf2f((unsigned short)(v >> 48));
  *(float4*)(out + ((size_t)b*S_ + t)*H_ + hcol) = o;
}

extern "C" void kernel_launch(void* const* d_in, const int* in_sizes, int n_in,
                              void* d_out, int out_size, void* d_ws, size_t ws_size,
                              hipStream_t stream){
  const float* x   = (const float*)d_in[0];
  const float* Wih = (const float*)d_in[1];
  const float* Whh = (const float*)d_in[2];
  const float* bih = (const float*)d_in[3];
  const float* bhh = (const float*)d_in[4];
  float* out = (float*)d_out;
  char* ws = (char*)d_ws;
  unsigned short* xaug     = (unsigned short*)(ws + OFF_XAUG);
  unsigned short* wihb     = (unsigned short*)(ws + OFF_WIHB);
  unsigned short* G        = (unsigned short*)(ws + OFF_G);
  unsigned long long* ring = (unsigned long long*)(ws + OFF_RING);   // overlays dead xaug

  sigk<<<NPOS, 256, 0, stream>>>(x, xaug);
  convk<<<(NG*KP + 255)/256, 256, 0, stream>>>(Wih, wihb);
  gemmk<<<dim3(256, 16), 256, 0, stream>>>(xaug, wihb, G);
  sentk<<<1024, 256, 0, stream>>>((uint4*)(ws + OFF_RING));          // after gemmk: xaug dead
  recurk<<<16, 256, 0, stream>>>(Whh, bih, bhh, G, out, ring);
  outk<<<16384, 256, 0, stream>>>(ring, out);
}

// Round 13
// 4908.694 us; speedup vs baseline: 1.1928x; 1.1928x over previous
//
#include <hip/hip_runtime.h>
#include <hip/hip_bf16.h>
#include <stdint.h>

typedef short bf16x8 __attribute__((ext_vector_type(8)));
typedef float f32x4 __attribute__((ext_vector_type(4)));

#define B_ 16
#define S_ 2048
#define H_ 512
#define NG 2048      // 4*H
#define KA 827
#define KP 832
#define NPOS (B_*S_)

// ---- workspace layout (bytes) ----
// ring overlays xaug (dead after gemmk; sentk re-initializes; its plain stores
// are L3-visible at dispatch end — proven by every passing round).
// ring: 2048 slots x 16 KiB, NO-REUSE, wave-major:
//   producer wave W's 128 h-values (8 h x 16 batches, bf16) live CONTIGUOUSLY at
//   u64 index W*32 + b*2 + kq  (kq in {0,1})  -> 4 cache lines per producer.
// ALL steps publish (incl. t=2047): the ring doubles as the bf16 ys archive that
// outk expands to f32 afterwards (R10-proven).
#define OFF_XAUG 0                     // NPOS*KP*2 = 54,525,952
#define OFF_WIHB 54525952              // NG*KP*2   =  3,407,872
#define OFF_G    57933824              // NPOS*NG*2 = 134,217,728 (ends 192,151,552)
#define OFF_RING 0                     // 33,554,432 B (< xaug size)
#define RING_U64_PER_SLOT 2048
#define SENT32 0x7F807F80u
#define SENT64 0x7F807F807F807F80ull   // 4x bf16 +inf; |h|<1 can never produce this

__device__ __forceinline__ unsigned short f2bf(float f){
  union { float f; unsigned u; } v; v.f = f;
  unsigned u = v.u;
  unsigned r = (u + 0x7FFFu + ((u >> 16) & 1u)) >> 16;
  return (unsigned short)r;
}
__device__ __forceinline__ float bf2f(unsigned short s){
  union { unsigned u; float f; } v; v.u = ((unsigned)s) << 16;
  return v.f;
}
__device__ __forceinline__ float sigf(float x){ return 1.0f / (1.0f + __expf(-x)); }
__device__ __forceinline__ float tanhfast(float x){ return 1.0f - 2.0f / (__expf(2.0f*x) + 1.0f); }

// ---------------- windowed signatures -> x_aug (bf16, K padded to 832) ----------------
__global__ __launch_bounds__(256) void sigk(const float* __restrict__ x,
                                            unsigned short* __restrict__ xaug){
  const int bid = blockIdx.x;
  const int s = bid >> 4, b = bid & 15;
  const int tid = threadIdx.x;
  __shared__ float win[10][9];
  __shared__ float s1b[2][9];
  __shared__ float s2b[2][81];
  if (tid < 90){
    int w = tid / 9, d = tid - w*9;
    int idx = s - 9 + w; if (idx < 0) idx = 0;
    win[w][d] = (d < 8) ? x[((size_t)b*S_ + idx)*8 + d] : (float)idx * (1.0f/2047.0f);
  }
  if (tid < 81) s2b[0][tid] = 0.0f;
  if (tid < 9)  s1b[0][tid] = 0.0f;
  __syncthreads();
  const int i0 = tid / 81;
  const int jj = (tid / 9) % 9;
  const int kk = tid % 9;
  float r0 = 0.0f, r1 = 0.0f, r2 = 0.0f;
  int p = 0;
  for (int w = 0; w < 10; ++w){
    if (tid < 243){
      float dj  = win[w][jj]   - (w ? win[w-1][jj]   : 0.0f);
      float dk  = win[w][kk]   - (w ? win[w-1][kk]   : 0.0f);
      float di0 = win[w][i0]   - (w ? win[w-1][i0]   : 0.0f);
      float di1 = win[w][i0+3] - (w ? win[w-1][i0+3] : 0.0f);
      float di2 = win[w][i0+6] - (w ? win[w-1][i0+6] : 0.0f);
      float e2 = 0.5f * dj * dk;
      float e3 = dj * dk * (1.0f/6.0f);
      r0 += s2b[p][i0*9+jj]*dk     + s1b[p][i0]*e2   + di0*e3;
      r1 += s2b[p][(i0+3)*9+jj]*dk + s1b[p][i0+3]*e2 + di1*e3;
      r2 += s2b[p][(i0+6)*9+jj]*dk + s1b[p][i0+6]*e2 + di2*e3;
    }
    if (tid < 81){
      int si = tid / 9, sj = tid - si*9;
      float dsi = win[w][si] - (w ? win[w-1][si] : 0.0f);
      float dsj = win[w][sj] - (w ? win[w-1][sj] : 0.0f);
      s2b[p^1][tid] = s2b[p][tid] + s1b[p][si]*dsj + 0.5f*dsi*dsj;
    }
    if (tid < 9){
      float dt = win[w][tid] - (w ? win[w-1][tid] : 0.0f);
      s1b[p^1][tid] = s1b[p][tid] + dt;
    }
    __syncthreads();
    p ^= 1;
  }
  unsigned short* row = xaug + (size_t)bid * KP;
  if (tid < 8)  row[tid]      = f2bf(x[((size_t)b*S_ + s)*8 + tid]);
  if (tid < 9)  row[8 + tid]  = f2bf(s1b[p][tid]);
  if (tid < 81) row[17 + tid] = f2bf(s2b[p][tid]);
  if (tid < 243){
    row[98 + tid]       = f2bf(r0);
    row[98 + tid + 243] = f2bf(r1);
    row[98 + tid + 486] = f2bf(r2);
  }
  if (tid < KP - KA) row[KA + tid] = 0;
}

// ---------------- W_ih f32 (2048x827) -> bf16 (2048x832 padded) ----------------
__global__ void convk(const float* __restrict__ W, unsigned short* __restrict__ o){
  int idx = blockIdx.x*256 + threadIdx.x;
  if (idx >= NG*KP) return;
  int n = idx / KP, k = idx - n*KP;
  o[idx] = (k < KA) ? f2bf(W[(size_t)n*KA + k]) : (unsigned short)0;
}

// ---------------- G = x_aug @ W_ih.T  (bf16 out) ----------------
__global__ __launch_bounds__(256) void gemmk(const unsigned short* __restrict__ A,
                                             const unsigned short* __restrict__ Bw,
                                             unsigned short* __restrict__ G){
  __shared__ unsigned short as[128][40];
  __shared__ unsigned short bs[128][40];
  const int tid = threadIdx.x;
  const int l = tid & 63, w = tid >> 6;
  const int wr = w >> 1, wc = w & 1;
  const int M0 = blockIdx.x * 128, N0 = blockIdx.y * 128;
  f32x4 acc[4][4];
  for (int i=0;i<4;i++) for (int j2=0;j2<4;j2++) acc[i][j2] = (f32x4){0,0,0,0};
  const int lrow = l & 15, kq8 = (l >> 4) * 8;
  for (int kt = 0; kt < 26; ++kt){
    const int kbase = kt * 32;
    for (int c = tid; c < 512; c += 256){
      int row = c >> 2, kc = (c & 3) * 8;
      uint4 va = *(const uint4*)(A  + (size_t)(M0 + row)*KP + kbase + kc);
      *(uint4*)(&as[row][kc]) = va;
      uint4 vb = *(const uint4*)(Bw + (size_t)(N0 + row)*KP + kbase + kc);
      *(uint4*)(&bs[row][kc]) = vb;
    }
    __syncthreads();
    bf16x8 af[4], bfv[4];
    for (int i=0;i<4;i++)    af[i]  = *(const bf16x8*)(&as[wr*64 + i*16 + lrow][kq8]);
    for (int j2=0;j2<4;j2++) bfv[j2] = *(const bf16x8*)(&bs[wc*64 + j2*16 + lrow][kq8]);
    for (int i=0;i<4;i++)
      for (int j2=0;j2<4;j2++)
        acc[i][j2] = __builtin_amdgcn_mfma_f32_16x16x32_bf16(af[i], bfv[j2], acc[i][j2], 0, 0, 0);
    __syncthreads();
  }
  const int rq = (l >> 4) * 4;
  for (int i=0;i<4;i++){
    for (int q=0;q<4;q++){
      int grow_ = M0 + wr*64 + i*16 + rq + q;
      unsigned short* gout = G + (size_t)grow_*NG + N0 + wc*64 + lrow;
      for (int j2=0;j2<4;j2++)
        gout[j2*16] = f2bf(acc[i][j2][q]);
    }
  }
}

// ---------------- init: sentinel-fill the 32 MiB no-reuse ring ----------------
__global__ __launch_bounds__(256) void sentk(uint4* __restrict__ ring){
  const size_t i = (size_t)blockIdx.x*256 + threadIdx.x;   // 1024 blocks -> 262144 threads
  uint4 s; s.x = SENT32; s.y = SENT32; s.z = SENT32; s.w = SENT32;
  #pragma unroll
  for (int k = 0; k < 8; ++k)
    ring[i + (size_t)k*262144] = s;                        // 2,097,152 uint4 = 32 MiB
}

// ---------------- LSTM recurrence: 64 autonomous waves, TWO-LEG sentinel exchange ----------------
// R9's proven batched-sweep structure VERBATIM; publish EVERY step (ring = bf16 ys
// archive, R10-proven); no ys stores here (outk expands). Best measured: 4.58 ms.
__global__ __launch_bounds__(64, 1) void recurk(const float* __restrict__ Whh,
    const float* __restrict__ bih, const float* __restrict__ bhh,
    const unsigned short* __restrict__ G, float* __restrict__ out,
    unsigned long long* __restrict__ ring){
  const int W = ((blockIdx.x & 7) << 3) | (blockIdx.x >> 3);  // G-line-sharing waves per XCD
  const int l = threadIdx.x;
  const int b = l & 15, kq = l >> 4;
  const int hbase = W * 8;

  // A fragments resident in registers (128 VGPRs)
  bf16x8 a0[16], a1[16];
  {
    const int p = l & 15;
    const int arow0 = (p < 8) ? (hbase + p) : (512 + hbase + (p - 8));
    const int arow1 = arow0 + 1024;
    const float* w0 = Whh + (size_t)arow0 * H_;
    const float* w1 = Whh + (size_t)arow1 * H_;
    for (int kk2 = 0; kk2 < 16; ++kk2){
      const int k0 = kk2*32 + kq*8;
      float4 v0 = *(const float4*)(w0 + k0);
      float4 v1 = *(const float4*)(w0 + k0 + 4);
      bf16x8 av;
      av[0]=(short)f2bf(v0.x); av[1]=(short)f2bf(v0.y); av[2]=(short)f2bf(v0.z); av[3]=(short)f2bf(v0.w);
      av[4]=(short)f2bf(v1.x); av[5]=(short)f2bf(v1.y); av[6]=(short)f2bf(v1.z); av[7]=(short)f2bf(v1.w);
      a0[kk2] = av;
      float4 u0 = *(const float4*)(w1 + k0);
      float4 u1 = *(const float4*)(w1 + k0 + 4);
      bf16x8 bv2;
      bv2[0]=(short)f2bf(u0.x); bv2[1]=(short)f2bf(u0.y); bv2[2]=(short)f2bf(u0.z); bv2[3]=(short)f2bf(u0.w);
      bv2[4]=(short)f2bf(u1.x); bv2[5]=(short)f2bf(u1.y); bv2[6]=(short)f2bf(u1.z); bv2[7]=(short)f2bf(u1.w);
      a1[kk2] = bv2;
    }
  }
  const int col0 = ((kq < 2) ? (kq*4) : (512 + (kq-2)*4)) + hbase;
  const int col1 = col0 + 1024;
  float bias0[4], bias1[4];
  #pragma unroll
  for (int q=0;q<4;q++){
    bias0[q] = bih[col0+q] + bhh[col0+q];
    bias1[q] = bih[col1+q] + bhh[col1+q];
  }
  const bool low = (kq < 2);
  const int hcol = hbase + (low ? kq*4 : (kq-2)*4);
  const size_t ownw = (size_t)W*32 + b*2 + kq;   // low-lane's ring word (u64 idx in slot)
  float cr[4] = {0,0,0,0};

  for (int t = 0; t < S_; ++t){
    // G prefetch (cacheable) issued before the sweep; HBM latency hides under it
    const unsigned short* gp = G + ((size_t)t*16 + b) * NG;
    const short4 g0 = *(const short4*)(gp + col0);
    const short4 g1 = *(const short4*)(gp + col1);

    f32x4 acc0 = (f32x4){0,0,0,0}, acc0b = (f32x4){0,0,0,0};
    f32x4 acc1 = (f32x4){0,0,0,0}, acc1b = (f32x4){0,0,0,0};
    if (t){
      // ---- sentinel sweep: 32 coalesced agent-atomic u64 loads, retry until clean ----
      const unsigned long long* sp = ring + (size_t)(t-1)*RING_U64_PER_SLOT;
      unsigned long long rv[32];
      for (;;){
        #pragma unroll
        for (int i = 0; i < 16; ++i){
          const size_t wi = (size_t)((i*4 + kq)*32 + b*2);   // dense 1KB window per instr
          rv[2*i]   = __hip_atomic_load(sp + wi,     __ATOMIC_RELAXED, __HIP_MEMORY_SCOPE_AGENT);
          rv[2*i+1] = __hip_atomic_load(sp + wi + 1, __ATOMIC_RELAXED, __HIP_MEMORY_SCOPE_AGENT);
        }
        unsigned ok = 1;
        #pragma unroll
        for (int i = 0; i < 32; ++i) ok &= (rv[i] != SENT64);
        if (__all((int)ok)) break;
      }
      #pragma unroll
      for (int i = 0; i < 8; ++i){
        uint2 lo0 = __builtin_bit_cast(uint2, rv[4*i]);
        uint2 hi0 = __builtin_bit_cast(uint2, rv[4*i+1]);
        uint4 u0v; u0v.x = lo0.x; u0v.y = lo0.y; u0v.z = hi0.x; u0v.w = hi0.y;
        bf16x8 bv0 = __builtin_bit_cast(bf16x8, u0v);
        acc0  = __builtin_amdgcn_mfma_f32_16x16x32_bf16(a0[2*i],   bv0, acc0,  0, 0, 0);
        acc1  = __builtin_amdgcn_mfma_f32_16x16x32_bf16(a1[2*i],   bv0, acc1,  0, 0, 0);
        uint2 lo1 = __builtin_bit_cast(uint2, rv[4*i+2]);
        uint2 hi1 = __builtin_bit_cast(uint2, rv[4*i+3]);
        uint4 u1v; u1v.x = lo1.x; u1v.y = lo1.y; u1v.z = hi1.x; u1v.w = hi1.y;
        bf16x8 bv1 = __builtin_bit_cast(bf16x8, u1v);
        acc0b = __builtin_amdgcn_mfma_f32_16x16x32_bf16(a0[2*i+1], bv1, acc0b, 0, 0, 0);
        acc1b = __builtin_amdgcn_mfma_f32_16x16x32_bf16(a1[2*i+1], bv1, acc1b, 0, 0, 0);
      }
    }
    float ga0[4] = { bf2f((unsigned short)g0.x), bf2f((unsigned short)g0.y),
                     bf2f((unsigned short)g0.z), bf2f((unsigned short)g0.w) };
    float ga1[4] = { bf2f((unsigned short)g1.x), bf2f((unsigned short)g1.y),
                     bf2f((unsigned short)g1.z), bf2f((unsigned short)g1.w) };
    float own0[4], own1[4], oth0[4], oth1[4];
    #pragma unroll
    for (int q=0;q<4;q++){
      own0[q] = (acc0[q] + acc0b[q]) + ga0[q] + bias0[q];
      own1[q] = (acc1[q] + acc1b[q]) + ga1[q] + bias1[q];
    }
    #pragma unroll
    for (int q=0;q<4;q++){
      oth0[q] = __shfl_xor(own0[q], 32, 64);
      oth1[q] = __shfl_xor(own1[q], 32, 64);
    }
    float h4[4];
    #pragma unroll
    for (int q=0;q<4;q++){
      float iv = low ? own0[q] : oth0[q];
      float fv = low ? oth0[q] : own0[q];
      float gv = low ? own1[q] : oth1[q];
      float ov = low ? oth1[q] : own1[q];
      cr[q] = sigf(fv)*cr[q] + sigf(iv)*tanhfast(gv);
      h4[q] = sigf(ov)*tanhfast(cr[q]);
    }
    if (low){
      // publish EVERY step: data is both the next-step signal and the ys archive
      unsigned long long pk = (unsigned long long)f2bf(h4[0])
                            | ((unsigned long long)f2bf(h4[1]) << 16)
                            | ((unsigned long long)f2bf(h4[2]) << 32)
                            | ((unsigned long long)f2bf(h4[3]) << 48);
      __hip_atomic_exchange(ring + (size_t)t*RING_U64_PER_SLOT + ownw,
                            pk, __ATOMIC_RELAXED, __HIP_MEMORY_SCOPE_AGENT);
      if (t == S_ - 1){
        float* hn = out + (size_t)B_*S_*H_;
        float* cn = hn + B_*H_;
        #pragma unroll
        for (int q=0;q<4;q++){
          hn[b*H_ + hcol + q] = h4[q];
          cn[b*H_ + hcol + q] = cr[q];
        }
      }
    }
  }
}

// ---------------- outk: expand ring (bf16 ys archive) -> out f32, fully coalesced ----------------
__global__ __launch_bounds__(256) void outk(const unsigned long long* __restrict__ ring,
                                            float* __restrict__ out){
  const size_t idx = (size_t)blockIdx.x*256 + threadIdx.x;   // 16*2048*128 = 4,194,304
  const int w = (int)(idx & 127);          // group of 4 h-cols
  const size_t bt = idx >> 7;
  const int t = (int)(bt & 2047);
  const int b = (int)(bt >> 11);
  const int hcol = w * 4;
  const int W = hcol >> 3;
  const int kq = (hcol >> 2) & 1;
  unsigned long long v = ring[(size_t)t*RING_U64_PER_SLOT + (size_t)W*32 + b*2 + kq];
  float4 o;
  o.x = bf2f((unsigned short)(v));
  o.y = bf2f((unsigned short)(v >> 16));
  o.z = bf2f((unsigned short)(v >> 32));
  o.w = bf2f((unsigned short)(v >> 48));
  *(float4*)(out + ((size_t)b*S_ + t)*H_ + hcol) = o;
}

extern "C" void kernel_launch(void* const* d_in, const int* in_sizes, int n_in,
                              void* d_out, int out_size, void* d_ws, size_t ws_size,
                              hipStream_t stream){
  const float* x   = (const float*)d_in[0];
  const float* Wih = (const float*)d_in[1];
  const float* Whh = (const float*)d_in[2];
  const float* bih = (const float*)d_in[3];
  const float* bhh = (const float*)d_in[4];
  float* out = (float*)d_out;
  char* ws = (char*)d_ws;
  unsigned short* xaug     = (unsigned short*)(ws + OFF_XAUG);
  unsigned short* wihb     = (unsigned short*)(ws + OFF_WIHB);
  unsigned short* G        = (unsigned short*)(ws + OFF_G);
  unsigned long long* ring = (unsigned long long*)(ws + OFF_RING);   // overlays dead xaug

  sigk<<<NPOS, 256, 0, stream>>>(x, xaug);
  convk<<<(NG*KP + 255)/256, 256, 0, stream>>>(Wih, wihb);
  gemmk<<<dim3(256, 16), 256, 0, stream>>>(xaug, wihb, G);
  sentk<<<1024, 256, 0, stream>>>((uint4*)(ws + OFF_RING));          // after gemmk: xaug dead
  recurk<<<64, 64, 0, stream>>>(Whh, bih, bhh, G, out, ring);
  outk<<<16384, 256, 0, stream>>>(ring, out);
}